// Round 1
// baseline (403.549 us; speedup 1.0000x reference)
//
#include <hip/hip_runtime.h>
#include <math.h>

// Problem constants (from setup_inputs)
#define N_DET 512
#define K_ANN 100
#define MH    28
#define MW    28
#define NPIX  (MH * MW)     // 784
#define IMH   800
#define IMW   800
#define IOU_THRESH 0.5f
#define EPS_F 1e-7f

// ws layout (first 12 bytes zeroed each launch):
//   wsi[0] : valid-detection count (int)
//   wsf[1] : running |diff| sum (float)
//   wsi[2] : blocks-done counter (int) -> last block finalizes out[0]

// ---------------- Single fused kernel ----------------
// Block n owns detection n:
//   phase 1: wave-0 shuffle argmax of IOU over 100 annotations (no LDS tree)
//   phase 2: if max_iou >= 0.5, all 256 threads do the 784-pixel bilinear
//            crop + stride-100 mask gather + |diff| reduce, one atomicAdd
//   phase 3: last-done block reads totals via device-scope atomics and
//            writes the final scalar (dispatch-order independent).
__global__ __launch_bounds__(256) void maskloss_fused(
    const float* __restrict__ det,    // (512,4) x1,y1,x2,y2
    const float* __restrict__ masks,  // (512,28,28,100)
    const float* __restrict__ ann,    // (100,4)
    const float* __restrict__ mt,     // (100,800,800)
    int*   __restrict__ wsi,
    float* __restrict__ wsf,
    float* __restrict__ out)
{
    __shared__ float s_iou;
    __shared__ int   s_k;
    __shared__ float wsum[4];

    const int n   = blockIdx.x;
    const int tid = threadIdx.x;

    const float dx1 = det[n * 4 + 0];
    const float dy1 = det[n * 4 + 1];
    const float dx2 = det[n * 4 + 2];
    const float dy2 = det[n * 4 + 3];

    // ---- phase 1: argmax IOU on wave 0 (lanes handle k and k+64) ----
    if (tid < 64) {
        const float darea = (dx2 - dx1) * (dy2 - dy1);
        float best = -1.0f;
        int   bidx = 0x7FFFFFFF;
        for (int k = tid; k < K_ANN; k += 64) {   // k, then k+64: strict '>' keeps smaller idx on tie
            const float ax1 = ann[k * 4 + 0];
            const float ay1 = ann[k * 4 + 1];
            const float ax2 = ann[k * 4 + 2];
            const float ay2 = ann[k * 4 + 3];
            const float area_k = (ax2 - ax1) * (ay2 - ay1);
            float iw = fminf(dx2, ax2) - fmaxf(dx1, ax1);
            float ih = fminf(dy2, ay2) - fmaxf(dy1, ay1);
            iw = fmaxf(iw, 0.0f);
            ih = fmaxf(ih, 0.0f);
            const float inter = iw * ih;
            const float ua = darea + area_k - inter;
            const float iou = inter / fmaxf(ua, EPS_F);
            if (iou > best) { best = iou; bidx = k; }
        }
        // 64-lane butterfly argmax; ties -> smaller index (jnp.argmax semantics)
        for (int m = 32; m > 0; m >>= 1) {
            const float ov = __shfl_xor(best, m);
            const int   oi = __shfl_xor(bidx, m);
            if (ov > best || (ov == best && oi < bidx)) { best = ov; bidx = oi; }
        }
        if (tid == 0) { s_iou = best; s_k = bidx; }
    }
    __syncthreads();

    const bool valid = (s_iou >= IOU_THRESH);   // block-uniform
    const int  k     = s_k;

    // ---- phase 2: pixel loss for valid detections ----
    if (valid) {
        // boxes = [y1/H, x1/W, y2/H, x2/W] — keep exact FP form of the verified kernel
        const float by1 = dy1 / (float)IMH;
        const float bx1 = dx1 / (float)IMW;
        const float by2 = dy2 / (float)IMH;
        const float bx2 = dx2 / (float)IMW;

        const float* __restrict__ img = mt    + (size_t)k * (IMH * IMW);
        const float* __restrict__ msk = masks + (size_t)n * (NPIX * K_ANN) + k;

        auto px = [&](int p) -> float {
            const int i = p / MW;
            const int j = p - i * MW;
            const float gy = (float)i * (1.0f / (float)(MH - 1));
            const float gx = (float)j * (1.0f / (float)(MW - 1));
            const float in_y = (by1 + (by2 - by1) * gy) * (float)(IMH - 1);
            const float in_x = (bx1 + (bx2 - bx1) * gx) * (float)(IMW - 1);
            const bool vy = (in_y >= 0.0f) && (in_y <= (float)(IMH - 1));
            const bool vx = (in_x >= 0.0f) && (in_x <= (float)(IMW - 1));
            const float y0f = floorf(in_y);
            const float x0f = floorf(in_x);
            const float yf = in_y - y0f;
            const float xf = in_x - x0f;
            int y0i = (int)y0f;
            int x0i = (int)x0f;
            y0i = min(max(y0i, 0), IMH - 1);
            x0i = min(max(x0i, 0), IMW - 1);
            const int y1i = min(y0i + 1, IMH - 1);
            const int x1i = min(x0i + 1, IMW - 1);

            const float msel = msk[(size_t)p * K_ANN];   // masks[n,i,j,k], stride-100 gather
            const float v00 = img[y0i * IMW + x0i];
            const float v01 = img[y0i * IMW + x1i];
            const float v10 = img[y1i * IMW + x0i];
            const float v11 = img[y1i * IMW + x1i];
            const float top = v00 + (v01 - v00) * xf;
            const float bot = v10 + (v11 - v10) * xf;
            float outv = top + (bot - top) * yf;
            outv = (vy && vx) ? outv : 0.0f;
            return fabsf(msel - outv);
        };

        // 784 = 3*256 + 16: three full strides (ILP across gathers) + tiny tail
        float local = px(tid) + px(tid + 256) + px(tid + 512);
        if (tid < 16) local += px(tid + 768);

        // 64-lane shuffle reduce, then cross-wave via LDS
        for (int off = 32; off > 0; off >>= 1)
            local += __shfl_down(local, off);
        const int wave = tid >> 6;
        const int lane = tid & 63;
        if (lane == 0) wsum[wave] = local;
        __syncthreads();
        if (tid == 0) {
            atomicAdd(&wsf[1], (wsum[0] + wsum[1]) + (wsum[2] + wsum[3]));
            atomicAdd(&wsi[0], 1);
        }
    }

    // ---- phase 3: last-done block finalizes (device-scope atomics only) ----
    __threadfence();
    if (tid == 0) {
        if (atomicAdd(&wsi[2], 1) == N_DET - 1) {
            const int   c = atomicAdd(&wsi[0], 0);        // atomic read-back (coherent)
            const float s = atomicAdd(&wsf[1], 0.0f);     // atomic read-back (coherent)
            out[0] = s / fmaxf((float)c * (float)NPIX, 1.0f);
        }
    }
}

extern "C" void kernel_launch(void* const* d_in, const int* in_sizes, int n_in,
                              void* d_out, int out_size, void* d_ws, size_t ws_size,
                              hipStream_t stream) {
    const float* det   = (const float*)d_in[0];  // detections (1,512,4)
    const float* masks = (const float*)d_in[1];  // masks (1,512,28,28,100)
    const float* ann   = (const float*)d_in[2];  // annotations (1,100,4)
    const float* mt    = (const float*)d_in[3];  // masks_target (1,100,800,800)
    float* out = (float*)d_out;
    int*   wsi = (int*)d_ws;
    float* wsf = (float*)d_ws;

    // ws is poisoned to 0xAA before every timed launch — zero count, sum, done.
    hipMemsetAsync(d_ws, 0, 3 * sizeof(int), stream);

    maskloss_fused<<<N_DET, 256, 0, stream>>>(det, masks, ann, mt, wsi, wsf, out);
}